// Round 10
// baseline (154.854 us; speedup 1.0000x reference)
//
#include <hip/hip_runtime.h>
#include <hip/hip_bf16.h>

typedef unsigned short u16;
typedef __attribute__((ext_vector_type(8))) short short8;
typedef __attribute__((ext_vector_type(8))) __bf16 bf16x8;
typedef __attribute__((ext_vector_type(4))) float f32x4;

#define DEV static __device__ __forceinline__

DEV float bf2f(u16 u) { unsigned v = ((unsigned)u) << 16; float f; __builtin_memcpy(&f, &v, 4); return f; }
DEV u16 f2bf(float f) {
  unsigned u; __builtin_memcpy(&u, &f, 4);
  unsigned lsb = (u >> 16) & 1;
  u += 0x7fffu + lsb;  // RNE
  return (u16)(u >> 16);
}
DEV u16 tbf(float f) {  // truncate (P in [0,1]: bias ~2^-10, harmless)
  unsigned u; __builtin_memcpy(&u, &f, 4);
  return (u16)(u >> 16);
}
DEV float exp2fast(float x) { return __builtin_amdgcn_exp2f(x); }  // v_exp_f32
DEV f32x4 mfma16(short8 a, short8 b, f32x4 c) {
  return __builtin_amdgcn_mfma_f32_16x16x32_bf16(
      __builtin_bit_cast(bf16x8, a), __builtin_bit_cast(bf16x8, b), c, 0, 0, 0);
}
DEV short8 ld8(const u16* p) { return *(const short8*)p; }

// ---------------- fused weight prep (round-4 proven) ----------------
__global__ void prep_all(const float* __restrict__ hw, const float* __restrict__ wo,
                         const float* __restrict__ w1, const float* __restrict__ w2,
                         u16* __restrict__ wqh, u16* __restrict__ wql,
                         u16* __restrict__ woT, u16* __restrict__ w1T, u16* __restrict__ w2T) {
  int idx = blockIdx.x * 256 + threadIdx.x;
  if (idx < 786432) {  // 8*512*192
    int e = idx % 192;
    int d = (idx / 192) % 512;
    int h = idx / (192 * 512);
    float v = hw[idx];
    int n = (e < 64) ? (h * 64 + e) : (e < 128) ? (512 + h * 64 + e - 64) : (1024 + h * 64 + e - 128);
    size_t oi = (size_t)n * 512 + d;
    u16 hh = f2bf(v);
    wqh[oi] = hh;
    if (e < 128) wql[oi] = f2bf(v - bf2f(hh));
  } else if (idx < 786432 + 262144) {
    int i = idx - 786432;  // wo: K=512, N=512
    int n = i % 512, k = i / 512;
    woT[(size_t)n * 512 + k] = f2bf(wo[i]);
  } else if (idx < 786432 + 262144 + 65536) {
    int i = idx - (786432 + 262144);  // w1: K=512, N=128
    int n = i % 128, k = i / 128;
    w1T[(size_t)n * 512 + k] = f2bf(w1[i]);
  } else if (idx < 786432 + 262144 + 131072) {
    int i = idx - (786432 + 262144 + 65536);  // w2: K=128, N=512
    int n = i % 512, k = i / 512;
    w2T[(size_t)n * 128 + k] = f2bf(w2[i]);
  }
}

// ---------------- LayerNorm: f32 (rows x 512) -> bf16 hi/lo ----------------
__global__ __launch_bounds__(256) void ln_kernel(const float* __restrict__ in,
                                                 const float* __restrict__ w,
                                                 const float* __restrict__ bb,
                                                 u16* __restrict__ hi, u16* __restrict__ lo) {
  const int wv = threadIdx.x >> 6, lane = threadIdx.x & 63;
  const int row = blockIdx.x * 4 + wv;
  const float4* r = (const float4*)(in + (size_t)row * 512);
  float4 a0 = r[lane * 2], a1 = r[lane * 2 + 1];
  float s = a0.x + a0.y + a0.z + a0.w + a1.x + a1.y + a1.z + a1.w;
  float ss = a0.x * a0.x + a0.y * a0.y + a0.z * a0.z + a0.w * a0.w +
             a1.x * a1.x + a1.y * a1.y + a1.z * a1.z + a1.w * a1.w;
#pragma unroll
  for (int m = 1; m < 64; m <<= 1) { s += __shfl_xor(s, m); ss += __shfl_xor(ss, m); }
  float mu = s * (1.f / 512.f);
  float var = ss * (1.f / 512.f) - mu * mu;
  float rstd = rsqrtf(var + 1e-5f);
  const float4* wp = (const float4*)w + lane * 2;
  const float4* bp = (const float4*)bb + lane * 2;
  float4 w0 = wp[0], w1v = wp[1], b0 = bp[0], b1v = bp[1];
  float xv[8] = {a0.x, a0.y, a0.z, a0.w, a1.x, a1.y, a1.z, a1.w};
  float wv8[8] = {w0.x, w0.y, w0.z, w0.w, w1v.x, w1v.y, w1v.z, w1v.w};
  float bv8[8] = {b0.x, b0.y, b0.z, b0.w, b1v.x, b1v.y, b1v.z, b1v.w};
  short8 oh, ol;
#pragma unroll
  for (int i = 0; i < 8; i++) {
    float v = (xv[i] - mu) * rstd * wv8[i] + bv8[i];
    u16 hh = f2bf(v);
    oh[i] = (short)hh;
    ol[i] = (short)f2bf(v - bf2f(hh));
  }
  *(short8*)(hi + (size_t)row * 512 + lane * 8) = oh;
  *(short8*)(lo + (size_t)row * 512 + lane * 8) = ol;
}

// ---------------- QKV GEMM: BM=128, BN=64, grid (32,24) ----------------
__global__ __launch_bounds__(256) void gemm_qkv(const u16* __restrict__ Ah, const u16* __restrict__ Alo,
                                                const u16* __restrict__ Bh, const u16* __restrict__ Blo,
                                                u16* __restrict__ outh, u16* __restrict__ outl) {
  __shared__ __align__(16) u16 As[128][40], Asl[128][40], Bs[64][40], Bsl[64][40];
  const int tid = threadIdx.x, lane = tid & 63, wv = tid >> 6;
  const int wm = wv >> 1, wn = wv & 1, g = lane >> 4, r16 = lane & 15;
  const int bm = blockIdx.x * 128, bn = blockIdx.y * 64;
  const bool split = blockIdx.y < 16;
  short8 sA[2], sAl[2], sB, sBl;
  auto ldtile = [&](int kt) {
#pragma unroll
    for (int c = 0; c < 2; c++) {
      int ch = c * 256 + tid;
      sA[c] = ld8(Ah + (size_t)(bm + (ch >> 2)) * 512 + kt + (ch & 3) * 8);
      if (split) sAl[c] = ld8(Alo + (size_t)(bm + (ch >> 2)) * 512 + kt + (ch & 3) * 8);
    }
    sB = ld8(Bh + (size_t)(bn + (tid >> 2)) * 512 + kt + (tid & 3) * 8);
    if (split) sBl = ld8(Blo + (size_t)(bn + (tid >> 2)) * 512 + kt + (tid & 3) * 8);
  };
  f32x4 acc[4][2] = {};
  ldtile(0);
  for (int kt = 0; kt < 512; kt += 32) {
    __syncthreads();
#pragma unroll
    for (int c = 0; c < 2; c++) {
      int ch = c * 256 + tid;
      *(short8*)&As[ch >> 2][(ch & 3) * 8] = sA[c];
      if (split) *(short8*)&Asl[ch >> 2][(ch & 3) * 8] = sAl[c];
    }
    *(short8*)&Bs[tid >> 2][(tid & 3) * 8] = sB;
    if (split) *(short8*)&Bsl[tid >> 2][(tid & 3) * 8] = sBl;
    __syncthreads();
    if (kt + 32 < 512) ldtile(kt + 32);
    short8 af[4], bf_[2], afl[4], bfl[2];
#pragma unroll
    for (int mi = 0; mi < 4; mi++) af[mi] = *(const short8*)&As[wm * 64 + mi * 16 + r16][g * 8];
#pragma unroll
    for (int ni = 0; ni < 2; ni++) bf_[ni] = *(const short8*)&Bs[wn * 32 + ni * 16 + r16][g * 8];
    if (split) {
#pragma unroll
      for (int mi = 0; mi < 4; mi++) afl[mi] = *(const short8*)&Asl[wm * 64 + mi * 16 + r16][g * 8];
#pragma unroll
      for (int ni = 0; ni < 2; ni++) bfl[ni] = *(const short8*)&Bsl[wn * 32 + ni * 16 + r16][g * 8];
    }
#pragma unroll
    for (int mi = 0; mi < 4; mi++)
#pragma unroll
      for (int ni = 0; ni < 2; ni++) {
        acc[mi][ni] = mfma16(af[mi], bf_[ni], acc[mi][ni]);
        if (split) {
          acc[mi][ni] = mfma16(af[mi], bfl[ni], acc[mi][ni]);
          acc[mi][ni] = mfma16(afl[mi], bf_[ni], acc[mi][ni]);
        }
      }
  }
#pragma unroll
  for (int mi = 0; mi < 4; mi++)
#pragma unroll
    for (int ni = 0; ni < 2; ni++) {
      int col = bn + wn * 32 + ni * 16 + r16;
      int row0 = bm + wm * 64 + mi * 16 + g * 4;
#pragma unroll
      for (int j = 0; j < 4; j++) {
        size_t oi = (size_t)(row0 + j) * 1536 + col;
        float v = acc[mi][ni][j];
        u16 hh = f2bf(v);
        outh[oi] = hh;
        if (split) outl[oi] = f2bf(v - bf2f(hh));
      }
    }
}

// ---------------- generic GEMM ----------------
template <int MF, int NF, int EPI>
__global__ __launch_bounds__(256) void gemm_g(const u16* __restrict__ A, const u16* __restrict__ BT,
                                              const float* __restrict__ res, const float* __restrict__ bias,
                                              u16* __restrict__ outb, float* __restrict__ outf,
                                              int N, int K) {
  constexpr int BM = 32 * MF, BN = 32 * NF;
  constexpr int CA = (BM * 4 + 255) / 256, CB = (BN * 4 + 255) / 256;
  __shared__ __align__(16) u16 As[BM][40], Bs[BN][40];
  const int tid = threadIdx.x, lane = tid & 63, wv = tid >> 6;
  const int wm = wv >> 1, wn = wv & 1, g = lane >> 4, r16 = lane & 15;
  const int bm = blockIdx.x * BM, bn = blockIdx.y * BN;
  short8 sA[CA], sB[CB];
  auto ldtile = [&](int kt) {
#pragma unroll
    for (int c = 0; c < CA; c++) {
      int ch = c * 256 + tid;
      if (ch < BM * 4) sA[c] = ld8(A + (size_t)(bm + (ch >> 2)) * K + kt + (ch & 3) * 8);
    }
#pragma unroll
    for (int c = 0; c < CB; c++) {
      int ch = c * 256 + tid;
      if (ch < BN * 4) sB[c] = ld8(BT + (size_t)(bn + (ch >> 2)) * K + kt + (ch & 3) * 8);
    }
  };
  f32x4 acc[MF][NF] = {};
  ldtile(0);
  for (int kt = 0; kt < K; kt += 32) {
    __syncthreads();
#pragma unroll
    for (int c = 0; c < CA; c++) {
      int ch = c * 256 + tid;
      if (ch < BM * 4) *(short8*)&As[ch >> 2][(ch & 3) * 8] = sA[c];
    }
#pragma unroll
    for (int c = 0; c < CB; c++) {
      int ch = c * 256 + tid;
      if (ch < BN * 4) *(short8*)&Bs[ch >> 2][(ch & 3) * 8] = sB[c];
    }
    __syncthreads();
    if (kt + 32 < K) ldtile(kt + 32);
    short8 af[MF], bf_[NF];
#pragma unroll
    for (int mi = 0; mi < MF; mi++) af[mi] = *(const short8*)&As[wm * 16 * MF + mi * 16 + r16][g * 8];
#pragma unroll
    for (int ni = 0; ni < NF; ni++) bf_[ni] = *(const short8*)&Bs[wn * 16 * NF + ni * 16 + r16][g * 8];
#pragma unroll
    for (int mi = 0; mi < MF; mi++)
#pragma unroll
      for (int ni = 0; ni < NF; ni++) acc[mi][ni] = mfma16(af[mi], bf_[ni], acc[mi][ni]);
  }
#pragma unroll
  for (int mi = 0; mi < MF; mi++)
#pragma unroll
    for (int ni = 0; ni < NF; ni++) {
      int col = bn + wn * 16 * NF + ni * 16 + r16;
      int row0 = bm + wm * 16 * MF + mi * 16 + g * 4;
#pragma unroll
      for (int j = 0; j < 4; j++) {
        size_t oi = (size_t)(row0 + j) * N + col;
        float v = acc[mi][ni][j];
        if (EPI == 1) {
          outf[oi] = v + res[oi];
        } else if (EPI == 2) {
          outb[oi] = f2bf(v + bias[col]);
        } else {
          float u = v + bias[col];
          float gl = 0.5f * u * (1.0f + erff(u * 0.70710678118f));
          outf[oi] = gl + res[oi];
        }
      }
    }
}

// ---------------- flash attention v8: 8-wave block, in-block kv-split, KVBLK=128/half ----------------
// Waves 0-3: kv [0,1024), waves 4-7: kv [1024,2048); 8 iterations of 128 kv each
// (vs 16 in r4/r9 -> half the barriers and softmax passes). r4-proven 8-f softmax body,
// r9-proven in-LDS merge. LDS 140KB -> 1 block/CU, 8 waves/CU.
__global__ __launch_bounds__(512, 2) void attn_kernel(const u16* __restrict__ qkv_hi,
                                                      const u16* __restrict__ qkv_lo,
                                                      u16* __restrict__ ob) {
  // u16 pool: Kh[half]@half*9216 (128x72) | Kl@18432+half*9216 | Vt@36864+half*8704 (64x136)
  // | Pw@54272+w*2176 (16x136). Total 71680 u16 = 143360 B.
  // Post-loop aliases (barrier-protected): oex f32[64][68] @ u16 0 (17408B, inside Kh[0..8704]);
  // mlx f32[64][2] @ u16 9216 (512B, inside Kh half-1 region).
  __shared__ __align__(16) u16 smem[71680];
  const int tid = threadIdx.x, lane = tid & 63, w = tid >> 6;
  const int half = w >> 2, wq = w & 3;
  const int g = lane >> 4, r16 = lane & 15;
  const int qb = blockIdx.x * 64;
  const int b = blockIdx.y >> 3, h = blockIdx.y & 7;
  const size_t bbase = (size_t)b * 2048 * 1536;
  const u16* Qh = qkv_hi + bbase + h * 64;
  const u16* Ql = qkv_lo + bbase + h * 64;
  const u16* KgH = qkv_hi + bbase + 512 + h * 64;
  const u16* KgL = qkv_lo + bbase + 512 + h * 64;
  const u16* Vg = qkv_hi + bbase + 1024 + h * 64;
  u16* Kh = smem + half * 9216;
  u16* Kl = smem + 18432 + half * 9216;
  u16* Vt = smem + 36864 + half * 8704;
  u16* Pw = smem + 54272 + w * 2176;

  const int qrow = qb + wq * 16 + r16;
  short8 qh[2], qlo[2];
#pragma unroll
  for (int ks = 0; ks < 2; ks++) {
    qh[ks] = ld8(Qh + (size_t)qrow * 1536 + ks * 32 + g * 8);
    qlo[ks] = ld8(Ql + (size_t)qrow * 1536 + ks * 32 + g * 8);
  }

  f32x4 oacc[4] = {};
  float m_r[4], l_r[4];
#pragma unroll
  for (int j = 0; j < 4; j++) { m_r[j] = -3e38f; l_r[j] = 0.f; }

  // per-half staging maps (256 threads/half):
  // K: row sr = th>>1 (0..127), cols (th&1)*32 .. +31 (4 short8 per buffer).
  // V: rows kv = lane and lane+64, cols wq*16 .. +15 (2 short8 per row).
  const int th = tid & 255;
  const int sr = th >> 1, sc32 = (th & 1) * 32;
  const int kv0 = half * 1024;
  short8 kA[4], kB[4], vS[4];
  auto ldkv = [&](int kt) {
    const u16* kp = KgH + (size_t)(kt + sr) * 1536 + sc32;
    const u16* lp = KgL + (size_t)(kt + sr) * 1536 + sc32;
#pragma unroll
    for (int c = 0; c < 4; c++) {
      kA[c] = ld8(kp + c * 8);
      kB[c] = ld8(lp + c * 8);
    }
    vS[0] = ld8(Vg + (size_t)(kt + lane) * 1536 + wq * 16);
    vS[1] = ld8(Vg + (size_t)(kt + lane) * 1536 + wq * 16 + 8);
    vS[2] = ld8(Vg + (size_t)(kt + 64 + lane) * 1536 + wq * 16);
    vS[3] = ld8(Vg + (size_t)(kt + 64 + lane) * 1536 + wq * 16 + 8);
  };
  ldkv(kv0);

  for (int kt = kv0; kt < kv0 + 1024; kt += 128) {
    __syncthreads();  // previous tile's LDS reads done
#pragma unroll
    for (int c = 0; c < 4; c++) {
      *(short8*)&Kh[sr * 72 + sc32 + c * 8] = kA[c];
      *(short8*)&Kl[sr * 72 + sc32 + c * 8] = kB[c];
    }
#pragma unroll
    for (int c2 = 0; c2 < 2; c2++)
#pragma unroll
      for (int i = 0; i < 8; i++) {
        Vt[(wq * 16 + c2 * 8 + i) * 136 + lane] = (u16)vS[c2][i];
        Vt[(wq * 16 + c2 * 8 + i) * 136 + 64 + lane] = (u16)vS[2 + c2][i];
      }
    __syncthreads();  // tile ready
    if (kt + 128 < kv0 + 1024) ldkv(kt + 128);  // prefetch next tile under compute
    // ---- QK^T (split: hi*hi + hi*lo + lo*hi), 8 f-tiles of 16 kv ----
    f32x4 s[8];
#pragma unroll
    for (int f = 0; f < 8; f++) {
      s[f] = f32x4{0.f, 0.f, 0.f, 0.f};
      int krow = f * 16 + r16;
#pragma unroll
      for (int ks = 0; ks < 2; ks++) {
        short8 bh = *(const short8*)&Kh[krow * 72 + ks * 32 + g * 8];
        short8 bl = *(const short8*)&Kl[krow * 72 + ks * 32 + g * 8];
        s[f] = mfma16(qh[ks], bh, s[f]);
        s[f] = mfma16(qh[ks], bl, s[f]);
        s[f] = mfma16(qlo[ks], bh, s[f]);
      }
    }
    // ---- online softmax (log2 domain, r4-proven 8-f form) ----
    constexpr float SCL2 = 0.125f * 1.44269504f;
    float scl[4];
#pragma unroll
    for (int j = 0; j < 4; j++) {
      float a[8];
#pragma unroll
      for (int f = 0; f < 8; f++) a[f] = s[f][j] * SCL2;
      float vm = fmaxf(fmaxf(fmaxf(a[0], a[1]), fmaxf(a[2], a[3])),
                       fmaxf(fmaxf(a[4], a[5]), fmaxf(a[6], a[7])));
      vm = fmaxf(vm, __shfl_xor(vm, 1));
      vm = fmaxf(vm, __shfl_xor(vm, 2));
      vm = fmaxf(vm, __shfl_xor(vm, 4));
      vm = fmaxf(vm, __shfl_xor(vm, 8));
      float mn = fmaxf(m_r[j], vm);
      float rs = 0.f;
      int pr = (g * 4 + j) * 136 + r16;
#pragma unroll
      for (int f = 0; f < 8; f++) {
        float e = exp2fast(a[f] - mn);
        rs += e;
        Pw[pr + f * 16] = tbf(e);
      }
      rs += __shfl_xor(rs, 1);
      rs += __shfl_xor(rs, 2);
      rs += __shfl_xor(rs, 4);
      rs += __shfl_xor(rs, 8);
      scl[j] = exp2fast(m_r[j] - mn);
      m_r[j] = mn;
      l_r[j] = l_r[j] * scl[j] + rs;
    }
#pragma unroll
    for (int dt = 0; dt < 4; dt++)
#pragma unroll
      for (int j = 0; j < 4; j++) oacc[dt][j] *= scl[j];
    // ---- P@V (4 k-slices of 32 kv) ----
#pragma unroll
    for (int ks = 0; ks < 4; ks++) {
      short8 pa = *(const short8*)&Pw[r16 * 136 + ks * 32 + g * 8];
#pragma unroll
      for (int dt = 0; dt < 4; dt++) {
        short8 vb = *(const short8*)&Vt[(dt * 16 + r16) * 136 + ks * 32 + g * 8];
        oacc[dt] = mfma16(pa, vb, oacc[dt]);
      }
    }
  }
  // ---- in-block merge of the two kv halves (r9-proven) ----
  __syncthreads();  // all waves done with K/V/P LDS
  float* oex = (float*)smem;            // [64 rows][68] f32
  float* mlx = (float*)(smem + 9216);   // [64 rows][2] f32
  if (half == 1) {
#pragma unroll
    for (int dt = 0; dt < 4; dt++)
#pragma unroll
      for (int j = 0; j < 4; j++)
        oex[(wq * 16 + g * 4 + j) * 68 + dt * 16 + r16] = oacc[dt][j];
    if (r16 == 0) {
#pragma unroll
      for (int j = 0; j < 4; j++) {
        mlx[(wq * 16 + g * 4 + j) * 2] = m_r[j];
        mlx[(wq * 16 + g * 4 + j) * 2 + 1] = l_r[j];
      }
    }
  }
  __syncthreads();
  if (half == 0) {
#pragma unroll
    for (int j = 0; j < 4; j++) {
      int rr = wq * 16 + g * 4 + j;
      float m1 = mlx[rr * 2], l1 = mlx[rr * 2 + 1];
      float mm = fmaxf(m_r[j], m1);
      float c0 = exp2fast(m_r[j] - mm), c1 = exp2fast(m1 - mm);
      float inv = 1.f / (c0 * l_r[j] + c1 * l1);
      c0 *= inv;
      c1 *= inv;
      int row = b * 2048 + qb + rr;
#pragma unroll
      for (int dt = 0; dt < 4; dt++) {
        float o1 = oex[rr * 68 + dt * 16 + r16];
        int col = h * 64 + dt * 16 + r16;
        ob[(size_t)row * 512 + col] = f2bf(oacc[dt][j] * c0 + o1 * c1);
      }
    }
  }
}

// ---------------- launcher ----------------
extern "C" void kernel_launch(void* const* d_in, const int* in_sizes, int n_in,
                              void* d_out, int out_size, void* d_ws, size_t ws_size,
                              hipStream_t stream) {
  const float* z = (const float*)d_in[0];
  const float* head_w = (const float*)d_in[1];
  const float* w_o = (const float*)d_in[2];
  const float* ln_w = (const float*)d_in[3];
  const float* ln_b = (const float*)d_in[4];
  const float* w1 = (const float*)d_in[5];
  const float* b1 = (const float*)d_in[6];
  const float* w2 = (const float*)d_in[7];
  const float* b2 = (const float*)d_in[8];
  float* out = (float*)d_out;

  size_t off = 0;
  auto alc = [&](size_t n) {
    void* p = (char*)d_ws + off;
    off += (n + 255) & ~(size_t)255;
    return p;
  };
  // footprint identical to the proven round-4 layout.
  u16* x_hi = (u16*)alc((size_t)4096 * 512 * 2);
  u16* x_lo = (u16*)alc((size_t)4096 * 512 * 2);
  u16* wqh = (u16*)alc((size_t)1536 * 512 * 2);
  u16* wql = (u16*)alc((size_t)1536 * 512 * 2);
  u16* woT = (u16*)alc((size_t)512 * 512 * 2);
  u16* w1T = (u16*)alc((size_t)128 * 512 * 2);
  u16* w2T = (u16*)alc((size_t)512 * 128 * 2);
  u16* qkvh = (u16*)alc((size_t)4096 * 1536 * 2);
  u16* qkvl = (u16*)alc((size_t)4096 * 1536 * 2);
  u16* ob = (u16*)alc((size_t)4096 * 512 * 2);
  float* z2 = (float*)alc((size_t)4096 * 512 * 4);
  u16* tb = (u16*)alc((size_t)4096 * 128 * 2);

  prep_all<<<4608, 256, 0, stream>>>(head_w, w_o, w1, w2, wqh, wql, woT, w1T, w2T);

  // LN1: z -> x hi/lo
  ln_kernel<<<1024, 256, 0, stream>>>(z, ln_w, ln_b, x_hi, x_lo);

  // QKV projection
  gemm_qkv<<<dim3(32, 24), 256, 0, stream>>>(x_hi, x_lo, wqh, wql, qkvh, qkvl);

  // flash attention: 512 blocks x 8 waves, in-block kv-split, KVBLK=128/half
  attn_kernel<<<dim3(32, 16), 512, 0, stream>>>(qkvh, qkvl, ob);

  // z2 = o @ w_o + z
  gemm_g<2, 2, 1><<<dim3(64, 8), 256, 0, stream>>>(ob, woT, z, nullptr, nullptr, z2, 512, 512);

  // LN2
  ln_kernel<<<1024, 256, 0, stream>>>(z2, ln_w, ln_b, x_hi, x_lo);

  // t = y @ w1 + b1
  gemm_g<1, 2, 2><<<dim3(128, 2), 256, 0, stream>>>(x_hi, w1T, nullptr, b1, tb, nullptr, 128, 512);

  // out = gelu(t @ w2 + b2) + z2
  gemm_g<2, 2, 3><<<dim3(64, 8), 256, 0, stream>>>(tb, w2T, z2, b2, nullptr, out, 512, 128);
}

// Round 11
// 146.947 us; speedup vs baseline: 1.0538x; 1.0538x over previous
//
#include <hip/hip_runtime.h>
#include <hip/hip_bf16.h>

typedef unsigned short u16;
typedef __attribute__((ext_vector_type(8))) short short8;
typedef __attribute__((ext_vector_type(8))) __bf16 bf16x8;
typedef __attribute__((ext_vector_type(4))) float f32x4;

#define DEV static __device__ __forceinline__

DEV float bf2f(u16 u) { unsigned v = ((unsigned)u) << 16; float f; __builtin_memcpy(&f, &v, 4); return f; }
DEV u16 f2bf(float f) {
  unsigned u; __builtin_memcpy(&u, &f, 4);
  unsigned lsb = (u >> 16) & 1;
  u += 0x7fffu + lsb;  // RNE
  return (u16)(u >> 16);
}
DEV u16 tbf(float f) {  // truncate (P in [0,1]: bias ~2^-10, harmless)
  unsigned u; __builtin_memcpy(&u, &f, 4);
  return (u16)(u >> 16);
}
DEV float exp2fast(float x) { return __builtin_amdgcn_exp2f(x); }  // v_exp_f32
DEV f32x4 mfma16(short8 a, short8 b, f32x4 c) {
  return __builtin_amdgcn_mfma_f32_16x16x32_bf16(
      __builtin_bit_cast(bf16x8, a), __builtin_bit_cast(bf16x8, b), c, 0, 0, 0);
}
DEV short8 ld8(const u16* p) { return *(const short8*)p; }

// ---------------- fused weight prep (round-4 proven) ----------------
__global__ void prep_all(const float* __restrict__ hw, const float* __restrict__ wo,
                         const float* __restrict__ w1, const float* __restrict__ w2,
                         u16* __restrict__ wqh, u16* __restrict__ wql,
                         u16* __restrict__ woT, u16* __restrict__ w1T, u16* __restrict__ w2T) {
  int idx = blockIdx.x * 256 + threadIdx.x;
  if (idx < 786432) {  // 8*512*192
    int e = idx % 192;
    int d = (idx / 192) % 512;
    int h = idx / (192 * 512);
    float v = hw[idx];
    int n = (e < 64) ? (h * 64 + e) : (e < 128) ? (512 + h * 64 + e - 64) : (1024 + h * 64 + e - 128);
    size_t oi = (size_t)n * 512 + d;
    u16 hh = f2bf(v);
    wqh[oi] = hh;
    if (e < 128) wql[oi] = f2bf(v - bf2f(hh));
  } else if (idx < 786432 + 262144) {
    int i = idx - 786432;  // wo: K=512, N=512
    int n = i % 512, k = i / 512;
    woT[(size_t)n * 512 + k] = f2bf(wo[i]);
  } else if (idx < 786432 + 262144 + 65536) {
    int i = idx - (786432 + 262144);  // w1: K=512, N=128
    int n = i % 128, k = i / 128;
    w1T[(size_t)n * 512 + k] = f2bf(w1[i]);
  } else if (idx < 786432 + 262144 + 131072) {
    int i = idx - (786432 + 262144 + 65536);  // w2: K=128, N=512
    int n = i % 512, k = i / 512;
    w2T[(size_t)n * 128 + k] = f2bf(w2[i]);
  }
}

// ---------------- LayerNorm: f32 (rows x 512) -> bf16 hi/lo ----------------
__global__ __launch_bounds__(256) void ln_kernel(const float* __restrict__ in,
                                                 const float* __restrict__ w,
                                                 const float* __restrict__ bb,
                                                 u16* __restrict__ hi, u16* __restrict__ lo) {
  const int wv = threadIdx.x >> 6, lane = threadIdx.x & 63;
  const int row = blockIdx.x * 4 + wv;
  const float4* r = (const float4*)(in + (size_t)row * 512);
  float4 a0 = r[lane * 2], a1 = r[lane * 2 + 1];
  float s = a0.x + a0.y + a0.z + a0.w + a1.x + a1.y + a1.z + a1.w;
  float ss = a0.x * a0.x + a0.y * a0.y + a0.z * a0.z + a0.w * a0.w +
             a1.x * a1.x + a1.y * a1.y + a1.z * a1.z + a1.w * a1.w;
#pragma unroll
  for (int m = 1; m < 64; m <<= 1) { s += __shfl_xor(s, m); ss += __shfl_xor(ss, m); }
  float mu = s * (1.f / 512.f);
  float var = ss * (1.f / 512.f) - mu * mu;
  float rstd = rsqrtf(var + 1e-5f);
  const float4* wp = (const float4*)w + lane * 2;
  const float4* bp = (const float4*)bb + lane * 2;
  float4 w0 = wp[0], w1v = wp[1], b0 = bp[0], b1v = bp[1];
  float xv[8] = {a0.x, a0.y, a0.z, a0.w, a1.x, a1.y, a1.z, a1.w};
  float wv8[8] = {w0.x, w0.y, w0.z, w0.w, w1v.x, w1v.y, w1v.z, w1v.w};
  float bv8[8] = {b0.x, b0.y, b0.z, b0.w, b1v.x, b1v.y, b1v.z, b1v.w};
  short8 oh, ol;
#pragma unroll
  for (int i = 0; i < 8; i++) {
    float v = (xv[i] - mu) * rstd * wv8[i] + bv8[i];
    u16 hh = f2bf(v);
    oh[i] = (short)hh;
    ol[i] = (short)f2bf(v - bf2f(hh));
  }
  *(short8*)(hi + (size_t)row * 512 + lane * 8) = oh;
  *(short8*)(lo + (size_t)row * 512 + lane * 8) = ol;
}

// ---------------- QKV GEMM v2: BM=128, BN=128, BK=64, grid (32,12) ----------------
// blockIdx.y<8: split path (Q,K cols: 3 MFMA, hi+lo out). else: plain V (1 MFMA, hi out).
// 4 waves, each owns a 64x64 output tile (4x4 f32x4 acc). 96 MFMA per barrier-pair (split).
__global__ __launch_bounds__(256) void gemm_qkv(const u16* __restrict__ Ah, const u16* __restrict__ Alo,
                                                const u16* __restrict__ Bh, const u16* __restrict__ Blo,
                                                u16* __restrict__ outh, u16* __restrict__ outl) {
  __shared__ __align__(16) u16 Ahs[128][72], Als[128][72], Bhs[128][72], Bls[128][72];
  const int tid = threadIdx.x, lane = tid & 63, wv = tid >> 6;
  const int wm = wv >> 1, wn = wv & 1, g = lane >> 4, r16 = lane & 15;
  const int bm = blockIdx.x * 128, bn = blockIdx.y * 128;
  const bool split = blockIdx.y < 8;
  // staging: thread -> row sr (0..127), 32-u16 chunk sc (0 or 32); 4 x short8 per buffer
  const int sr = tid >> 1, sc = (tid & 1) * 32;
  short8 a_h[4], a_l[4], b_h[4], b_l[4];
  auto ldtile = [&](int kt) {
    const u16* pa = Ah + (size_t)(bm + sr) * 512 + kt + sc;
    const u16* pb = Bh + (size_t)(bn + sr) * 512 + kt + sc;
#pragma unroll
    for (int c = 0; c < 4; c++) {
      a_h[c] = ld8(pa + c * 8);
      b_h[c] = ld8(pb + c * 8);
    }
    if (split) {
      const u16* qa = Alo + (size_t)(bm + sr) * 512 + kt + sc;
      const u16* qb = Blo + (size_t)(bn + sr) * 512 + kt + sc;
#pragma unroll
      for (int c = 0; c < 4; c++) {
        a_l[c] = ld8(qa + c * 8);
        b_l[c] = ld8(qb + c * 8);
      }
    }
  };
  f32x4 acc[4][4] = {};
  ldtile(0);
  for (int kt = 0; kt < 512; kt += 64) {
    __syncthreads();
#pragma unroll
    for (int c = 0; c < 4; c++) {
      *(short8*)&Ahs[sr][sc + c * 8] = a_h[c];
      *(short8*)&Bhs[sr][sc + c * 8] = b_h[c];
    }
    if (split) {
#pragma unroll
      for (int c = 0; c < 4; c++) {
        *(short8*)&Als[sr][sc + c * 8] = a_l[c];
        *(short8*)&Bls[sr][sc + c * 8] = b_l[c];
      }
    }
    __syncthreads();
    if (kt + 64 < 512) ldtile(kt + 64);
#pragma unroll
    for (int ks = 0; ks < 2; ks++) {
      short8 af[4], bf_[4], afl[4], bfl[4];
#pragma unroll
      for (int mi = 0; mi < 4; mi++) af[mi] = *(const short8*)&Ahs[wm * 64 + mi * 16 + r16][ks * 32 + g * 8];
#pragma unroll
      for (int ni = 0; ni < 4; ni++) bf_[ni] = *(const short8*)&Bhs[wn * 64 + ni * 16 + r16][ks * 32 + g * 8];
      if (split) {
#pragma unroll
        for (int mi = 0; mi < 4; mi++) afl[mi] = *(const short8*)&Als[wm * 64 + mi * 16 + r16][ks * 32 + g * 8];
#pragma unroll
        for (int ni = 0; ni < 4; ni++) bfl[ni] = *(const short8*)&Bls[wn * 64 + ni * 16 + r16][ks * 32 + g * 8];
      }
#pragma unroll
      for (int mi = 0; mi < 4; mi++)
#pragma unroll
        for (int ni = 0; ni < 4; ni++) {
          acc[mi][ni] = mfma16(af[mi], bf_[ni], acc[mi][ni]);
          if (split) {
            acc[mi][ni] = mfma16(af[mi], bfl[ni], acc[mi][ni]);
            acc[mi][ni] = mfma16(afl[mi], bf_[ni], acc[mi][ni]);
          }
        }
    }
  }
#pragma unroll
  for (int mi = 0; mi < 4; mi++)
#pragma unroll
    for (int ni = 0; ni < 4; ni++) {
      int col = bn + wn * 64 + ni * 16 + r16;
      int row0 = bm + wm * 64 + mi * 16 + g * 4;
#pragma unroll
      for (int j = 0; j < 4; j++) {
        size_t oi = (size_t)(row0 + j) * 1536 + col;
        float v = acc[mi][ni][j];
        u16 hh = f2bf(v);
        outh[oi] = hh;
        if (split) outl[oi] = f2bf(v - bf2f(hh));
      }
    }
}

// ---------------- generic GEMM ----------------
template <int MF, int NF, int EPI>
__global__ __launch_bounds__(256) void gemm_g(const u16* __restrict__ A, const u16* __restrict__ BT,
                                              const float* __restrict__ res, const float* __restrict__ bias,
                                              u16* __restrict__ outb, float* __restrict__ outf,
                                              int N, int K) {
  constexpr int BM = 32 * MF, BN = 32 * NF;
  constexpr int CA = (BM * 4 + 255) / 256, CB = (BN * 4 + 255) / 256;
  __shared__ __align__(16) u16 As[BM][40], Bs[BN][40];
  const int tid = threadIdx.x, lane = tid & 63, wv = tid >> 6;
  const int wm = wv >> 1, wn = wv & 1, g = lane >> 4, r16 = lane & 15;
  const int bm = blockIdx.x * BM, bn = blockIdx.y * BN;
  short8 sA[CA], sB[CB];
  auto ldtile = [&](int kt) {
#pragma unroll
    for (int c = 0; c < CA; c++) {
      int ch = c * 256 + tid;
      if (ch < BM * 4) sA[c] = ld8(A + (size_t)(bm + (ch >> 2)) * K + kt + (ch & 3) * 8);
    }
#pragma unroll
    for (int c = 0; c < CB; c++) {
      int ch = c * 256 + tid;
      if (ch < BN * 4) sB[c] = ld8(BT + (size_t)(bn + (ch >> 2)) * K + kt + (ch & 3) * 8);
    }
  };
  f32x4 acc[MF][NF] = {};
  ldtile(0);
  for (int kt = 0; kt < K; kt += 32) {
    __syncthreads();
#pragma unroll
    for (int c = 0; c < CA; c++) {
      int ch = c * 256 + tid;
      if (ch < BM * 4) *(short8*)&As[ch >> 2][(ch & 3) * 8] = sA[c];
    }
#pragma unroll
    for (int c = 0; c < CB; c++) {
      int ch = c * 256 + tid;
      if (ch < BN * 4) *(short8*)&Bs[ch >> 2][(ch & 3) * 8] = sB[c];
    }
    __syncthreads();
    if (kt + 32 < K) ldtile(kt + 32);
    short8 af[MF], bf_[NF];
#pragma unroll
    for (int mi = 0; mi < MF; mi++) af[mi] = *(const short8*)&As[wm * 16 * MF + mi * 16 + r16][g * 8];
#pragma unroll
    for (int ni = 0; ni < NF; ni++) bf_[ni] = *(const short8*)&Bs[wn * 16 * NF + ni * 16 + r16][g * 8];
#pragma unroll
    for (int mi = 0; mi < MF; mi++)
#pragma unroll
      for (int ni = 0; ni < NF; ni++) acc[mi][ni] = mfma16(af[mi], bf_[ni], acc[mi][ni]);
  }
#pragma unroll
  for (int mi = 0; mi < MF; mi++)
#pragma unroll
    for (int ni = 0; ni < NF; ni++) {
      int col = bn + wn * 16 * NF + ni * 16 + r16;
      int row0 = bm + wm * 16 * MF + mi * 16 + g * 4;
#pragma unroll
      for (int j = 0; j < 4; j++) {
        size_t oi = (size_t)(row0 + j) * N + col;
        float v = acc[mi][ni][j];
        if (EPI == 1) {
          outf[oi] = v + res[oi];
        } else if (EPI == 2) {
          outb[oi] = f2bf(v + bias[col]);
        } else {
          float u = v + bias[col];
          float gl = 0.5f * u * (1.0f + erff(u * 0.70710678118f));
          outf[oi] = gl + res[oi];
        }
      }
    }
}

// ---------------- flash attention (round-4 EXACT): QBLK=64 (4 waves x 16 rows), KVBLK=128 ----------------
__global__ __launch_bounds__(256) void attn_kernel(const u16* __restrict__ qkv_hi,
                                                   const u16* __restrict__ qkv_lo,
                                                   u16* __restrict__ o) {
  constexpr int SK = 72, SV = 136, SP = 136;
  __shared__ __align__(16) u16 Kh[128 * SK], Kl[128 * SK], Vt[64 * SV];
  __shared__ __align__(16) u16 Pl[4][16 * SP];
  const int tid = threadIdx.x, lane = tid & 63, w = tid >> 6;
  const int g = lane >> 4, r16 = lane & 15;
  const int qb = blockIdx.x * 64;
  const int b = blockIdx.y >> 3, h = blockIdx.y & 7;
  const size_t bbase = (size_t)b * 2048 * 1536;
  const u16* Qh = qkv_hi + bbase + h * 64;
  const u16* Ql = qkv_lo + bbase + h * 64;
  const u16* KgH = qkv_hi + bbase + 512 + h * 64;
  const u16* KgL = qkv_lo + bbase + 512 + h * 64;
  const u16* Vg = qkv_hi + bbase + 1024 + h * 64;

  const int qrow = qb + w * 16 + r16;
  short8 qh[2], qlo[2];
#pragma unroll
  for (int ks = 0; ks < 2; ks++) {
    qh[ks] = ld8(Qh + (size_t)qrow * 1536 + ks * 32 + g * 8);
    qlo[ks] = ld8(Ql + (size_t)qrow * 1536 + ks * 32 + g * 8);
  }

  f32x4 oacc[4] = {};
  float m_r[4], l_r[4];
#pragma unroll
  for (int j = 0; j < 4; j++) { m_r[j] = -3e38f; l_r[j] = 0.f; }

  short8 kA[4], kB[4], vS[4];
  auto ldkv = [&](int kt) {
#pragma unroll
    for (int c = 0; c < 4; c++) {
      int ch = c * 256 + tid;
      int kr = ch >> 3, kc = (ch & 7) * 8;
      kA[c] = ld8(KgH + (size_t)(kt + kr) * 1536 + kc);
      kB[c] = ld8(KgL + (size_t)(kt + kr) * 1536 + kc);
    }
#pragma unroll
    for (int c = 0; c < 2; c++)
#pragma unroll
      for (int c2 = 0; c2 < 2; c2++)
        vS[c * 2 + c2] = ld8(Vg + (size_t)(kt + c * 64 + lane) * 1536 + w * 16 + c2 * 8);
  };
  ldkv(0);

  for (int kt = 0; kt < 2048; kt += 128) {
    __syncthreads();
#pragma unroll
    for (int c = 0; c < 4; c++) {
      int ch = c * 256 + tid;
      int kr = ch >> 3, kc = (ch & 7) * 8;
      *(short8*)&Kh[kr * SK + kc] = kA[c];
      *(short8*)&Kl[kr * SK + kc] = kB[c];
    }
#pragma unroll
    for (int c = 0; c < 2; c++)
#pragma unroll
      for (int c2 = 0; c2 < 2; c2++)
#pragma unroll
        for (int i = 0; i < 8; i++)
          Vt[(w * 16 + c2 * 8 + i) * SV + c * 64 + lane] = (u16)vS[c * 2 + c2][i];
    __syncthreads();
    if (kt + 128 < 2048) ldkv(kt + 128);
    // ---- QK^T (split: hi*hi + hi*lo + lo*hi) ----
    f32x4 s[8];
#pragma unroll
    for (int f = 0; f < 8; f++) {
      s[f] = f32x4{0.f, 0.f, 0.f, 0.f};
#pragma unroll
      for (int ks = 0; ks < 2; ks++) {
        short8 bh = *(const short8*)&Kh[(f * 16 + r16) * SK + ks * 32 + g * 8];
        short8 bl = *(const short8*)&Kl[(f * 16 + r16) * SK + ks * 32 + g * 8];
        s[f] = mfma16(qh[ks], bh, s[f]);
        s[f] = mfma16(qh[ks], bl, s[f]);
        s[f] = mfma16(qlo[ks], bh, s[f]);
      }
    }
    // ---- online softmax in log2 domain ----
    constexpr float SCL2 = 0.125f * 1.44269504f;
    float scl[4];
#pragma unroll
    for (int j = 0; j < 4; j++) {
      float a[8];
#pragma unroll
      for (int f = 0; f < 8; f++) a[f] = s[f][j] * SCL2;
      float vm = fmaxf(fmaxf(fmaxf(a[0], a[1]), fmaxf(a[2], a[3])),
                       fmaxf(fmaxf(a[4], a[5]), fmaxf(a[6], a[7])));
      vm = fmaxf(vm, __shfl_xor(vm, 1));
      vm = fmaxf(vm, __shfl_xor(vm, 2));
      vm = fmaxf(vm, __shfl_xor(vm, 4));
      vm = fmaxf(vm, __shfl_xor(vm, 8));
      float mn = fmaxf(m_r[j], vm);
      float rs = 0.f;
      int pr = (g * 4 + j) * SP + r16;
#pragma unroll
      for (int f = 0; f < 8; f++) {
        float e = exp2fast(a[f] - mn);
        rs += e;
        Pl[w][pr + f * 16] = tbf(e);
      }
      rs += __shfl_xor(rs, 1);
      rs += __shfl_xor(rs, 2);
      rs += __shfl_xor(rs, 4);
      rs += __shfl_xor(rs, 8);
      scl[j] = exp2fast(m_r[j] - mn);
      m_r[j] = mn;
      l_r[j] = l_r[j] * scl[j] + rs;
    }
#pragma unroll
    for (int dt = 0; dt < 4; dt++)
#pragma unroll
      for (int j = 0; j < 4; j++) oacc[dt][j] *= scl[j];
    // ---- P@V ----
#pragma unroll
    for (int ks = 0; ks < 4; ks++) {
      short8 pa = *(const short8*)&Pl[w][r16 * SP + ks * 32 + g * 8];
#pragma unroll
      for (int dt = 0; dt < 4; dt++) {
        short8 vb = *(const short8*)&Vt[(dt * 16 + r16) * SV + ks * 32 + g * 8];
        oacc[dt] = mfma16(pa, vb, oacc[dt]);
      }
    }
  }
  float il[4];
#pragma unroll
  for (int j = 0; j < 4; j++) il[j] = 1.f / l_r[j];
#pragma unroll
  for (int dt = 0; dt < 4; dt++)
#pragma unroll
    for (int j = 0; j < 4; j++) {
      int row = b * 2048 + qb + w * 16 + g * 4 + j;
      int col = h * 64 + dt * 16 + r16;
      o[(size_t)row * 512 + col] = f2bf(oacc[dt][j] * il[j]);
    }
}

// ---------------- launcher ----------------
extern "C" void kernel_launch(void* const* d_in, const int* in_sizes, int n_in,
                              void* d_out, int out_size, void* d_ws, size_t ws_size,
                              hipStream_t stream) {
  const float* z = (const float*)d_in[0];
  const float* head_w = (const float*)d_in[1];
  const float* w_o = (const float*)d_in[2];
  const float* ln_w = (const float*)d_in[3];
  const float* ln_b = (const float*)d_in[4];
  const float* w1 = (const float*)d_in[5];
  const float* b1 = (const float*)d_in[6];
  const float* w2 = (const float*)d_in[7];
  const float* b2 = (const float*)d_in[8];
  float* out = (float*)d_out;

  size_t off = 0;
  auto alc = [&](size_t n) {
    void* p = (char*)d_ws + off;
    off += (n + 255) & ~(size_t)255;
    return p;
  };
  u16* x_hi = (u16*)alc((size_t)4096 * 512 * 2);
  u16* x_lo = (u16*)alc((size_t)4096 * 512 * 2);
  u16* wqh = (u16*)alc((size_t)1536 * 512 * 2);
  u16* wql = (u16*)alc((size_t)1536 * 512 * 2);
  u16* woT = (u16*)alc((size_t)512 * 512 * 2);
  u16* w1T = (u16*)alc((size_t)128 * 512 * 2);
  u16* w2T = (u16*)alc((size_t)512 * 128 * 2);
  u16* qkvh = (u16*)alc((size_t)4096 * 1536 * 2);
  u16* qkvl = (u16*)alc((size_t)4096 * 1536 * 2);
  u16* ob = (u16*)alc((size_t)4096 * 512 * 2);
  float* z2 = (float*)alc((size_t)4096 * 512 * 4);
  u16* tb = (u16*)alc((size_t)4096 * 128 * 2);

  prep_all<<<4608, 256, 0, stream>>>(head_w, w_o, w1, w2, wqh, wql, woT, w1T, w2T);

  // LN1: z -> x hi/lo
  ln_kernel<<<1024, 256, 0, stream>>>(z, ln_w, ln_b, x_hi, x_lo);

  // QKV projection: 128x128 tiles, BK=64, grid (32,12)
  gemm_qkv<<<dim3(32, 12), 256, 0, stream>>>(x_hi, x_lo, wqh, wql, qkvh, qkvl);

  // flash attention (round-4 exact, 512 blocks, KVBLK=128)
  attn_kernel<<<dim3(32, 16), 256, 0, stream>>>(qkvh, qkvl, ob);

  // z2 = o @ w_o + z
  gemm_g<2, 2, 1><<<dim3(64, 8), 256, 0, stream>>>(ob, woT, z, nullptr, nullptr, z2, 512, 512);

  // LN2
  ln_kernel<<<1024, 256, 0, stream>>>(z2, ln_w, ln_b, x_hi, x_lo);

  // t = y @ w1 + b1
  gemm_g<1, 2, 2><<<dim3(128, 2), 256, 0, stream>>>(x_hi, w1T, nullptr, b1, tb, nullptr, 128, 512);

  // out = gelu(t @ w2 + b2) + z2
  gemm_g<2, 2, 3><<<dim3(64, 8), 256, 0, stream>>>(tb, w2T, z2, b2, nullptr, out, 512, 128);
}

// Round 12
// 137.638 us; speedup vs baseline: 1.1251x; 1.0676x over previous
//
#include <hip/hip_runtime.h>
#include <hip/hip_bf16.h>

typedef unsigned short u16;
typedef __attribute__((ext_vector_type(8))) short short8;
typedef __attribute__((ext_vector_type(8))) __bf16 bf16x8;
typedef __attribute__((ext_vector_type(4))) float f32x4;

#define DEV static __device__ __forceinline__

DEV float bf2f(u16 u) { unsigned v = ((unsigned)u) << 16; float f; __builtin_memcpy(&f, &v, 4); return f; }
DEV u16 f2bf(float f) {
  unsigned u; __builtin_memcpy(&u, &f, 4);
  unsigned lsb = (u >> 16) & 1;
  u += 0x7fffu + lsb;  // RNE
  return (u16)(u >> 16);
}
DEV u16 tbf(float f) {  // truncate (P in [0,1]: bias ~2^-10, harmless)
  unsigned u; __builtin_memcpy(&u, &f, 4);
  return (u16)(u >> 16);
}
DEV float exp2fast(float x) { return __builtin_amdgcn_exp2f(x); }  // v_exp_f32
DEV f32x4 mfma16(short8 a, short8 b, f32x4 c) {
  return __builtin_amdgcn_mfma_f32_16x16x32_bf16(
      __builtin_bit_cast(bf16x8, a), __builtin_bit_cast(bf16x8, b), c, 0, 0, 0);
}
DEV short8 ld8(const u16* p) { return *(const short8*)p; }

// ---------------- fused weight prep (round-4 proven; output layout unchanged) ----------------
__global__ void prep_all(const float* __restrict__ hw, const float* __restrict__ wo,
                         const float* __restrict__ w1, const float* __restrict__ w2,
                         u16* __restrict__ wqh, u16* __restrict__ wql,
                         u16* __restrict__ woT, u16* __restrict__ w1T, u16* __restrict__ w2T) {
  int idx = blockIdx.x * 256 + threadIdx.x;
  if (idx < 786432) {  // 8*512*192
    int e = idx % 192;
    int d = (idx / 192) % 512;
    int h = idx / (192 * 512);
    float v = hw[idx];
    int n = (e < 64) ? (h * 64 + e) : (e < 128) ? (512 + h * 64 + e - 64) : (1024 + h * 64 + e - 128);
    size_t oi = (size_t)n * 512 + d;
    u16 hh = f2bf(v);
    wqh[oi] = hh;
    if (e < 128) wql[oi] = f2bf(v - bf2f(hh));
  } else if (idx < 786432 + 262144) {
    int i = idx - 786432;  // wo: K=512, N=512
    int n = i % 512, k = i / 512;
    woT[(size_t)n * 512 + k] = f2bf(wo[i]);
  } else if (idx < 786432 + 262144 + 65536) {
    int i = idx - (786432 + 262144);  // w1: K=512, N=128
    int n = i % 128, k = i / 128;
    w1T[(size_t)n * 512 + k] = f2bf(w1[i]);
  } else if (idx < 786432 + 262144 + 131072) {
    int i = idx - (786432 + 262144 + 65536);  // w2: K=128, N=512
    int n = i % 512, k = i / 512;
    w2T[(size_t)n * 128 + k] = f2bf(w2[i]);
  }
}

// ---------------- LayerNorm: f32 (rows x 512) -> bf16 hi/lo ----------------
__global__ __launch_bounds__(256) void ln_kernel(const float* __restrict__ in,
                                                 const float* __restrict__ w,
                                                 const float* __restrict__ bb,
                                                 u16* __restrict__ hi, u16* __restrict__ lo) {
  const int wv = threadIdx.x >> 6, lane = threadIdx.x & 63;
  const int row = blockIdx.x * 4 + wv;
  const float4* r = (const float4*)(in + (size_t)row * 512);
  float4 a0 = r[lane * 2], a1 = r[lane * 2 + 1];
  float s = a0.x + a0.y + a0.z + a0.w + a1.x + a1.y + a1.z + a1.w;
  float ss = a0.x * a0.x + a0.y * a0.y + a0.z * a0.z + a0.w * a0.w +
             a1.x * a1.x + a1.y * a1.y + a1.z * a1.z + a1.w * a1.w;
#pragma unroll
  for (int m = 1; m < 64; m <<= 1) { s += __shfl_xor(s, m); ss += __shfl_xor(ss, m); }
  float mu = s * (1.f / 512.f);
  float var = ss * (1.f / 512.f) - mu * mu;
  float rstd = rsqrtf(var + 1e-5f);
  const float4* wp = (const float4*)w + lane * 2;
  const float4* bp = (const float4*)bb + lane * 2;
  float4 w0 = wp[0], w1v = wp[1], b0 = bp[0], b1v = bp[1];
  float xv[8] = {a0.x, a0.y, a0.z, a0.w, a1.x, a1.y, a1.z, a1.w};
  float wv8[8] = {w0.x, w0.y, w0.z, w0.w, w1v.x, w1v.y, w1v.z, w1v.w};
  float bv8[8] = {b0.x, b0.y, b0.z, b0.w, b1v.x, b1v.y, b1v.z, b1v.w};
  short8 oh, ol;
#pragma unroll
  for (int i = 0; i < 8; i++) {
    float v = (xv[i] - mu) * rstd * wv8[i] + bv8[i];
    u16 hh = f2bf(v);
    oh[i] = (short)hh;
    ol[i] = (short)f2bf(v - bf2f(hh));
  }
  *(short8*)(hi + (size_t)row * 512 + lane * 8) = oh;
  *(short8*)(lo + (size_t)row * 512 + lane * 8) = ol;
}

// ---------------- QKV GEMM (r4 structure): BM=128, BN=64, grid (32,24) ----------------
// y<16: split path (Q,K cols -> qk[4096][1024] hi+lo). y>=16: V path -> vT[512][4096] (transposed!).
__global__ __launch_bounds__(256) void gemm_qkv(const u16* __restrict__ Ah, const u16* __restrict__ Alo,
                                                const u16* __restrict__ Bh, const u16* __restrict__ Blo,
                                                u16* __restrict__ qkh, u16* __restrict__ qkl,
                                                u16* __restrict__ vT) {
  __shared__ __align__(16) u16 As[128][40], Asl[128][40], Bs[64][40], Bsl[64][40];
  const int tid = threadIdx.x, lane = tid & 63, wv = tid >> 6;
  const int wm = wv >> 1, wn = wv & 1, g = lane >> 4, r16 = lane & 15;
  const int bm = blockIdx.x * 128, bn = blockIdx.y * 64;
  const bool split = blockIdx.y < 16;
  short8 sA[2], sAl[2], sB, sBl;
  auto ldtile = [&](int kt) {
#pragma unroll
    for (int c = 0; c < 2; c++) {
      int ch = c * 256 + tid;
      sA[c] = ld8(Ah + (size_t)(bm + (ch >> 2)) * 512 + kt + (ch & 3) * 8);
      if (split) sAl[c] = ld8(Alo + (size_t)(bm + (ch >> 2)) * 512 + kt + (ch & 3) * 8);
    }
    sB = ld8(Bh + (size_t)(bn + (tid >> 2)) * 512 + kt + (tid & 3) * 8);
    if (split) sBl = ld8(Blo + (size_t)(bn + (tid >> 2)) * 512 + kt + (tid & 3) * 8);
  };
  f32x4 acc[4][2] = {};
  ldtile(0);
  for (int kt = 0; kt < 512; kt += 32) {
    __syncthreads();
#pragma unroll
    for (int c = 0; c < 2; c++) {
      int ch = c * 256 + tid;
      *(short8*)&As[ch >> 2][(ch & 3) * 8] = sA[c];
      if (split) *(short8*)&Asl[ch >> 2][(ch & 3) * 8] = sAl[c];
    }
    *(short8*)&Bs[tid >> 2][(tid & 3) * 8] = sB;
    if (split) *(short8*)&Bsl[tid >> 2][(tid & 3) * 8] = sBl;
    __syncthreads();
    if (kt + 32 < 512) ldtile(kt + 32);
    short8 af[4], bf_[2], afl[4], bfl[2];
#pragma unroll
    for (int mi = 0; mi < 4; mi++) af[mi] = *(const short8*)&As[wm * 64 + mi * 16 + r16][g * 8];
#pragma unroll
    for (int ni = 0; ni < 2; ni++) bf_[ni] = *(const short8*)&Bs[wn * 32 + ni * 16 + r16][g * 8];
    if (split) {
#pragma unroll
      for (int mi = 0; mi < 4; mi++) afl[mi] = *(const short8*)&Asl[wm * 64 + mi * 16 + r16][g * 8];
#pragma unroll
      for (int ni = 0; ni < 2; ni++) bfl[ni] = *(const short8*)&Bsl[wn * 32 + ni * 16 + r16][g * 8];
    }
#pragma unroll
    for (int mi = 0; mi < 4; mi++)
#pragma unroll
      for (int ni = 0; ni < 2; ni++) {
        acc[mi][ni] = mfma16(af[mi], bf_[ni], acc[mi][ni]);
        if (split) {
          acc[mi][ni] = mfma16(af[mi], bfl[ni], acc[mi][ni]);
          acc[mi][ni] = mfma16(afl[mi], bf_[ni], acc[mi][ni]);
        }
      }
  }
#pragma unroll
  for (int mi = 0; mi < 4; mi++)
#pragma unroll
    for (int ni = 0; ni < 2; ni++) {
      int col = bn + wn * 32 + ni * 16 + r16;
      int row0 = bm + wm * 64 + mi * 16 + g * 4;
      if (split) {
#pragma unroll
        for (int j = 0; j < 4; j++) {
          size_t oi = (size_t)(row0 + j) * 1024 + col;
          float v = acc[mi][ni][j];
          u16 hh = f2bf(v);
          qkh[oi] = hh;
          qkl[oi] = f2bf(v - bf2f(hh));
        }
      } else {
        // V transposed: vT[vcol][row]; 4 row-consecutive values -> one 8B store
        int vcol = col - 1024;
        ushort4 pk;
        pk.x = f2bf(acc[mi][ni][0]);
        pk.y = f2bf(acc[mi][ni][1]);
        pk.z = f2bf(acc[mi][ni][2]);
        pk.w = f2bf(acc[mi][ni][3]);
        *(ushort4*)(vT + (size_t)vcol * 4096 + row0) = pk;
      }
    }
}

// ---------------- generic GEMM ----------------
template <int MF, int NF, int EPI>
__global__ __launch_bounds__(256) void gemm_g(const u16* __restrict__ A, const u16* __restrict__ BT,
                                              const float* __restrict__ res, const float* __restrict__ bias,
                                              u16* __restrict__ outb, float* __restrict__ outf,
                                              int N, int K) {
  constexpr int BM = 32 * MF, BN = 32 * NF;
  constexpr int CA = (BM * 4 + 255) / 256, CB = (BN * 4 + 255) / 256;
  __shared__ __align__(16) u16 As[BM][40], Bs[BN][40];
  const int tid = threadIdx.x, lane = tid & 63, wv = tid >> 6;
  const int wm = wv >> 1, wn = wv & 1, g = lane >> 4, r16 = lane & 15;
  const int bm = blockIdx.x * BM, bn = blockIdx.y * BN;
  short8 sA[CA], sB[CB];
  auto ldtile = [&](int kt) {
#pragma unroll
    for (int c = 0; c < CA; c++) {
      int ch = c * 256 + tid;
      if (ch < BM * 4) sA[c] = ld8(A + (size_t)(bm + (ch >> 2)) * K + kt + (ch & 3) * 8);
    }
#pragma unroll
    for (int c = 0; c < CB; c++) {
      int ch = c * 256 + tid;
      if (ch < BN * 4) sB[c] = ld8(BT + (size_t)(bn + (ch >> 2)) * K + kt + (ch & 3) * 8);
    }
  };
  f32x4 acc[MF][NF] = {};
  ldtile(0);
  for (int kt = 0; kt < K; kt += 32) {
    __syncthreads();
#pragma unroll
    for (int c = 0; c < CA; c++) {
      int ch = c * 256 + tid;
      if (ch < BM * 4) *(short8*)&As[ch >> 2][(ch & 3) * 8] = sA[c];
    }
#pragma unroll
    for (int c = 0; c < CB; c++) {
      int ch = c * 256 + tid;
      if (ch < BN * 4) *(short8*)&Bs[ch >> 2][(ch & 3) * 8] = sB[c];
    }
    __syncthreads();
    if (kt + 32 < K) ldtile(kt + 32);
    short8 af[MF], bf_[NF];
#pragma unroll
    for (int mi = 0; mi < MF; mi++) af[mi] = *(const short8*)&As[wm * 16 * MF + mi * 16 + r16][g * 8];
#pragma unroll
    for (int ni = 0; ni < NF; ni++) bf_[ni] = *(const short8*)&Bs[wn * 16 * NF + ni * 16 + r16][g * 8];
#pragma unroll
    for (int mi = 0; mi < MF; mi++)
#pragma unroll
      for (int ni = 0; ni < NF; ni++) acc[mi][ni] = mfma16(af[mi], bf_[ni], acc[mi][ni]);
  }
#pragma unroll
  for (int mi = 0; mi < MF; mi++)
#pragma unroll
    for (int ni = 0; ni < NF; ni++) {
      int col = bn + wn * 16 * NF + ni * 16 + r16;
      int row0 = bm + wm * 16 * MF + mi * 16 + g * 4;
#pragma unroll
      for (int j = 0; j < 4; j++) {
        size_t oi = (size_t)(row0 + j) * N + col;
        float v = acc[mi][ni][j];
        if (EPI == 1) {
          outf[oi] = v + res[oi];
        } else if (EPI == 2) {
          outb[oi] = f2bf(v + bias[col]);
        } else {
          float u = v + bias[col];
          float gl = 0.5f * u * (1.0f + erff(u * 0.70710678118f));
          outf[oi] = gl + res[oi];
        }
      }
    }
}

// ---------------- flash attention (r4 structure, V from pre-transposed vT) ----------------
// QBLK=64 (4 waves x 16 rows), KVBLK=128, grid (32,16).
// Q/K from qk[4096][1024] hi/lo; V staged from vT[512][4096] via b128 (no in-kernel transpose).
__global__ __launch_bounds__(256) void attn_kernel(const u16* __restrict__ qkh,
                                                   const u16* __restrict__ qkl,
                                                   const u16* __restrict__ vT,
                                                   u16* __restrict__ o) {
  constexpr int SK = 72, SV = 136, SP = 136;
  __shared__ __align__(16) u16 Kh[128 * SK], Kl[128 * SK], Vt[64 * SV];
  __shared__ __align__(16) u16 Pl[4][16 * SP];
  const int tid = threadIdx.x, lane = tid & 63, w = tid >> 6;
  const int g = lane >> 4, r16 = lane & 15;
  const int qb = blockIdx.x * 64;
  const int b = blockIdx.y >> 3, h = blockIdx.y & 7;
  const size_t bbase = (size_t)b * 2048 * 1024;
  const u16* Qh = qkh + bbase + h * 64;
  const u16* Ql = qkl + bbase + h * 64;
  const u16* KgH = qkh + bbase + 512 + h * 64;
  const u16* KgL = qkl + bbase + 512 + h * 64;
  const u16* Vtg = vT + (size_t)h * 64 * 4096 + (size_t)b * 2048;  // row d (0..63), col kv

  const int qrow = qb + w * 16 + r16;
  short8 qh[2], qlo[2];
#pragma unroll
  for (int ks = 0; ks < 2; ks++) {
    qh[ks] = ld8(Qh + (size_t)qrow * 1024 + ks * 32 + g * 8);
    qlo[ks] = ld8(Ql + (size_t)qrow * 1024 + ks * 32 + g * 8);
  }

  f32x4 oacc[4] = {};
  float m_r[4], l_r[4];
#pragma unroll
  for (int j = 0; j < 4; j++) { m_r[j] = -3e38f; l_r[j] = 0.f; }

  // staging maps: K: 4 b128/thread over 128 rows x 64 u16. V: d0 = tid>>4 (0..15), kv8 = (tid&15)*8,
  // 4 b128 at d = d0 + c*16 -> 256B-contiguous global segments per 16-lane group.
  const int vd0 = tid >> 4, vkv = (tid & 15) * 8;
  short8 kA[4], kB[4], vS[4];
  auto ldkv = [&](int kt) {
#pragma unroll
    for (int c = 0; c < 4; c++) {
      int ch = c * 256 + tid;
      int kr = ch >> 3, kc = (ch & 7) * 8;
      kA[c] = ld8(KgH + (size_t)(kt + kr) * 1024 + kc);
      kB[c] = ld8(KgL + (size_t)(kt + kr) * 1024 + kc);
    }
#pragma unroll
    for (int c = 0; c < 4; c++)
      vS[c] = ld8(Vtg + (size_t)(vd0 + c * 16) * 4096 + kt + vkv);
  };
  ldkv(0);

  for (int kt = 0; kt < 2048; kt += 128) {
    __syncthreads();
#pragma unroll
    for (int c = 0; c < 4; c++) {
      int ch = c * 256 + tid;
      int kr = ch >> 3, kc = (ch & 7) * 8;
      *(short8*)&Kh[kr * SK + kc] = kA[c];
      *(short8*)&Kl[kr * SK + kc] = kB[c];
    }
#pragma unroll
    for (int c = 0; c < 4; c++)
      *(short8*)&Vt[(vd0 + c * 16) * SV + vkv] = vS[c];
    __syncthreads();
    if (kt + 128 < 2048) ldkv(kt + 128);
    // ---- QK^T (split: hi*hi + hi*lo + lo*hi) ----
    f32x4 s[8];
#pragma unroll
    for (int f = 0; f < 8; f++) {
      s[f] = f32x4{0.f, 0.f, 0.f, 0.f};
#pragma unroll
      for (int ks = 0; ks < 2; ks++) {
        short8 bh = *(const short8*)&Kh[(f * 16 + r16) * SK + ks * 32 + g * 8];
        short8 bl = *(const short8*)&Kl[(f * 16 + r16) * SK + ks * 32 + g * 8];
        s[f] = mfma16(qh[ks], bh, s[f]);
        s[f] = mfma16(qh[ks], bl, s[f]);
        s[f] = mfma16(qlo[ks], bh, s[f]);
      }
    }
    // ---- online softmax in log2 domain ----
    constexpr float SCL2 = 0.125f * 1.44269504f;
    float scl[4];
#pragma unroll
    for (int j = 0; j < 4; j++) {
      float a[8];
#pragma unroll
      for (int f = 0; f < 8; f++) a[f] = s[f][j] * SCL2;
      float vm = fmaxf(fmaxf(fmaxf(a[0], a[1]), fmaxf(a[2], a[3])),
                       fmaxf(fmaxf(a[4], a[5]), fmaxf(a[6], a[7])));
      vm = fmaxf(vm, __shfl_xor(vm, 1));
      vm = fmaxf(vm, __shfl_xor(vm, 2));
      vm = fmaxf(vm, __shfl_xor(vm, 4));
      vm = fmaxf(vm, __shfl_xor(vm, 8));
      float mn = fmaxf(m_r[j], vm);
      float rs = 0.f;
      int pr = (g * 4 + j) * SP + r16;
#pragma unroll
      for (int f = 0; f < 8; f++) {
        float e = exp2fast(a[f] - mn);
        rs += e;
        Pl[w][pr + f * 16] = tbf(e);
      }
      rs += __shfl_xor(rs, 1);
      rs += __shfl_xor(rs, 2);
      rs += __shfl_xor(rs, 4);
      rs += __shfl_xor(rs, 8);
      scl[j] = exp2fast(m_r[j] - mn);
      m_r[j] = mn;
      l_r[j] = l_r[j] * scl[j] + rs;
    }
#pragma unroll
    for (int dt = 0; dt < 4; dt++)
#pragma unroll
      for (int j = 0; j < 4; j++) oacc[dt][j] *= scl[j];
    // ---- P@V ----
#pragma unroll
    for (int ks = 0; ks < 4; ks++) {
      short8 pa = *(const short8*)&Pl[w][r16 * SP + ks * 32 + g * 8];
#pragma unroll
      for (int dt = 0; dt < 4; dt++) {
        short8 vb = *(const short8*)&Vt[(dt * 16 + r16) * SV + ks * 32 + g * 8];
        oacc[dt] = mfma16(pa, vb, oacc[dt]);
      }
    }
  }
  float il[4];
#pragma unroll
  for (int j = 0; j < 4; j++) il[j] = 1.f / l_r[j];
#pragma unroll
  for (int dt = 0; dt < 4; dt++)
#pragma unroll
    for (int j = 0; j < 4; j++) {
      int row = b * 2048 + qb + w * 16 + g * 4 + j;
      int col = h * 64 + dt * 16 + r16;
      o[(size_t)row * 512 + col] = f2bf(oacc[dt][j] * il[j]);
    }
}

// ---------------- launcher ----------------
extern "C" void kernel_launch(void* const* d_in, const int* in_sizes, int n_in,
                              void* d_out, int out_size, void* d_ws, size_t ws_size,
                              hipStream_t stream) {
  const float* z = (const float*)d_in[0];
  const float* head_w = (const float*)d_in[1];
  const float* w_o = (const float*)d_in[2];
  const float* ln_w = (const float*)d_in[3];
  const float* ln_b = (const float*)d_in[4];
  const float* w1 = (const float*)d_in[5];
  const float* b1 = (const float*)d_in[6];
  const float* w2 = (const float*)d_in[7];
  const float* b2 = (const float*)d_in[8];
  float* out = (float*)d_out;

  size_t off = 0;
  auto alc = [&](size_t n) {
    void* p = (char*)d_ws + off;
    off += (n + 255) & ~(size_t)255;
    return p;
  };
  // footprint <= proven round-4 layout (qk split into 8+8MB, vT 4MB; was 12+12MB).
  u16* x_hi = (u16*)alc((size_t)4096 * 512 * 2);
  u16* x_lo = (u16*)alc((size_t)4096 * 512 * 2);
  u16* wqh = (u16*)alc((size_t)1536 * 512 * 2);
  u16* wql = (u16*)alc((size_t)1536 * 512 * 2);
  u16* woT = (u16*)alc((size_t)512 * 512 * 2);
  u16* w1T = (u16*)alc((size_t)128 * 512 * 2);
  u16* w2T = (u16*)alc((size_t)512 * 128 * 2);
  u16* qkh = (u16*)alc((size_t)4096 * 1024 * 2);
  u16* qkl = (u16*)alc((size_t)4096 * 1024 * 2);
  u16* vT = (u16*)alc((size_t)512 * 4096 * 2);
  u16* ob = (u16*)alc((size_t)4096 * 512 * 2);
  float* z2 = (float*)alc((size_t)4096 * 512 * 4);
  u16* tb = (u16*)alc((size_t)4096 * 128 * 2);

  prep_all<<<4608, 256, 0, stream>>>(head_w, w_o, w1, w2, wqh, wql, woT, w1T, w2T);

  // LN1: z -> x hi/lo
  ln_kernel<<<1024, 256, 0, stream>>>(z, ln_w, ln_b, x_hi, x_lo);

  // QKV projection (r4 tiling); V written transposed to vT
  gemm_qkv<<<dim3(32, 24), 256, 0, stream>>>(x_hi, x_lo, wqh, wql, qkh, qkl, vT);

  // flash attention (V staged from vT, b128 only)
  attn_kernel<<<dim3(32, 16), 256, 0, stream>>>(qkh, qkl, vT, ob);

  // z2 = o @ w_o + z
  gemm_g<2, 2, 1><<<dim3(64, 8), 256, 0, stream>>>(ob, woT, z, nullptr, nullptr, z2, 512, 512);

  // LN2
  ln_kernel<<<1024, 256, 0, stream>>>(z2, ln_w, ln_b, x_hi, x_lo);

  // t = y @ w1 + b1
  gemm_g<1, 2, 2><<<dim3(128, 2), 256, 0, stream>>>(x_hi, w1T, nullptr, b1, tb, nullptr, 128, 512);

  // out = gelu(t @ w2 + b2) + z2
  gemm_g<2, 2, 3><<<dim3(64, 8), 256, 0, stream>>>(tb, w2T, z2, b2, nullptr, out, 512, 128);
}

// Round 13
// 128.167 us; speedup vs baseline: 1.2082x; 1.0739x over previous
//
#include <hip/hip_runtime.h>
#include <hip/hip_bf16.h>

typedef unsigned short u16;
typedef unsigned int u32;
typedef __attribute__((ext_vector_type(8))) short short8;
typedef __attribute__((ext_vector_type(8))) __bf16 bf16x8;
typedef __attribute__((ext_vector_type(4))) float f32x4;

#define DEV static __device__ __forceinline__

DEV float bf2f(u16 u) { unsigned v = ((unsigned)u) << 16; float f; __builtin_memcpy(&f, &v, 4); return f; }
DEV u16 f2bf(float f) {
  unsigned u; __builtin_memcpy(&u, &f, 4);
  unsigned lsb = (u >> 16) & 1;
  u += 0x7fffu + lsb;  // RNE
  return (u16)(u >> 16);
}
DEV u16 tbf(float f) {  // truncate (P in [0,1]: bias ~2^-10, harmless)
  unsigned u; __builtin_memcpy(&u, &f, 4);
  return (u16)(u >> 16);
}
DEV float exp2fast(float x) { return __builtin_amdgcn_exp2f(x); }  // v_exp_f32
DEV f32x4 mfma16(short8 a, short8 b, f32x4 c) {
  return __builtin_amdgcn_mfma_f32_16x16x32_bf16(
      __builtin_bit_cast(bf16x8, a), __builtin_bit_cast(bf16x8, b), c, 0, 0, 0);
}
DEV short8 ld8(const u16* p) { return *(const short8*)p; }

// ---------------- fused weight prep (round-4 proven; output layout unchanged) ----------------
__global__ void prep_all(const float* __restrict__ hw, const float* __restrict__ wo,
                         const float* __restrict__ w1, const float* __restrict__ w2,
                         u16* __restrict__ wqh, u16* __restrict__ wql,
                         u16* __restrict__ woT, u16* __restrict__ w1T, u16* __restrict__ w2T) {
  int idx = blockIdx.x * 256 + threadIdx.x;
  if (idx < 786432) {  // 8*512*192
    int e = idx % 192;
    int d = (idx / 192) % 512;
    int h = idx / (192 * 512);
    float v = hw[idx];
    int n = (e < 64) ? (h * 64 + e) : (e < 128) ? (512 + h * 64 + e - 64) : (1024 + h * 64 + e - 128);
    size_t oi = (size_t)n * 512 + d;
    u16 hh = f2bf(v);
    wqh[oi] = hh;
    if (e < 128) wql[oi] = f2bf(v - bf2f(hh));
  } else if (idx < 786432 + 262144) {
    int i = idx - 786432;  // wo: K=512, N=512
    int n = i % 512, k = i / 512;
    woT[(size_t)n * 512 + k] = f2bf(wo[i]);
  } else if (idx < 786432 + 262144 + 65536) {
    int i = idx - (786432 + 262144);  // w1: K=512, N=128
    int n = i % 128, k = i / 128;
    w1T[(size_t)n * 512 + k] = f2bf(w1[i]);
  } else if (idx < 786432 + 262144 + 131072) {
    int i = idx - (786432 + 262144 + 65536);  // w2: K=128, N=512
    int n = i % 512, k = i / 512;
    w2T[(size_t)n * 128 + k] = f2bf(w2[i]);
  }
}

// ---------------- LayerNorm: f32 (rows x 512) -> bf16 hi/lo ----------------
__global__ __launch_bounds__(256) void ln_kernel(const float* __restrict__ in,
                                                 const float* __restrict__ w,
                                                 const float* __restrict__ bb,
                                                 u16* __restrict__ hi, u16* __restrict__ lo) {
  const int wv = threadIdx.x >> 6, lane = threadIdx.x & 63;
  const int row = blockIdx.x * 4 + wv;
  const float4* r = (const float4*)(in + (size_t)row * 512);
  float4 a0 = r[lane * 2], a1 = r[lane * 2 + 1];
  float s = a0.x + a0.y + a0.z + a0.w + a1.x + a1.y + a1.z + a1.w;
  float ss = a0.x * a0.x + a0.y * a0.y + a0.z * a0.z + a0.w * a0.w +
             a1.x * a1.x + a1.y * a1.y + a1.z * a1.z + a1.w * a1.w;
#pragma unroll
  for (int m = 1; m < 64; m <<= 1) { s += __shfl_xor(s, m); ss += __shfl_xor(ss, m); }
  float mu = s * (1.f / 512.f);
  float var = ss * (1.f / 512.f) - mu * mu;
  float rstd = rsqrtf(var + 1e-5f);
  const float4* wp = (const float4*)w + lane * 2;
  const float4* bp = (const float4*)bb + lane * 2;
  float4 w0 = wp[0], w1v = wp[1], b0 = bp[0], b1v = bp[1];
  float xv[8] = {a0.x, a0.y, a0.z, a0.w, a1.x, a1.y, a1.z, a1.w};
  float wv8[8] = {w0.x, w0.y, w0.z, w0.w, w1v.x, w1v.y, w1v.z, w1v.w};
  float bv8[8] = {b0.x, b0.y, b0.z, b0.w, b1v.x, b1v.y, b1v.z, b1v.w};
  short8 oh, ol;
#pragma unroll
  for (int i = 0; i < 8; i++) {
    float v = (xv[i] - mu) * rstd * wv8[i] + bv8[i];
    u16 hh = f2bf(v);
    oh[i] = (short)hh;
    ol[i] = (short)f2bf(v - bf2f(hh));
  }
  *(short8*)(hi + (size_t)row * 512 + lane * 8) = oh;
  *(short8*)(lo + (size_t)row * 512 + lane * 8) = ol;
}

// ---------------- QKV GEMM (r4 structure): BM=128, BN=64, grid (32,24) ----------------
// y<16: split path (Q,K cols -> qk[4096][1024] hi+lo). y>=16: V path -> vT[512][4096] (transposed!).
__global__ __launch_bounds__(256) void gemm_qkv(const u16* __restrict__ Ah, const u16* __restrict__ Alo,
                                                const u16* __restrict__ Bh, const u16* __restrict__ Blo,
                                                u16* __restrict__ qkh, u16* __restrict__ qkl,
                                                u16* __restrict__ vT) {
  __shared__ __align__(16) u16 As[128][40], Asl[128][40], Bs[64][40], Bsl[64][40];
  const int tid = threadIdx.x, lane = tid & 63, wv = tid >> 6;
  const int wm = wv >> 1, wn = wv & 1, g = lane >> 4, r16 = lane & 15;
  const int bm = blockIdx.x * 128, bn = blockIdx.y * 64;
  const bool split = blockIdx.y < 16;
  short8 sA[2], sAl[2], sB, sBl;
  auto ldtile = [&](int kt) {
#pragma unroll
    for (int c = 0; c < 2; c++) {
      int ch = c * 256 + tid;
      sA[c] = ld8(Ah + (size_t)(bm + (ch >> 2)) * 512 + kt + (ch & 3) * 8);
      if (split) sAl[c] = ld8(Alo + (size_t)(bm + (ch >> 2)) * 512 + kt + (ch & 3) * 8);
    }
    sB = ld8(Bh + (size_t)(bn + (tid >> 2)) * 512 + kt + (tid & 3) * 8);
    if (split) sBl = ld8(Blo + (size_t)(bn + (tid >> 2)) * 512 + kt + (tid & 3) * 8);
  };
  f32x4 acc[4][2] = {};
  ldtile(0);
  for (int kt = 0; kt < 512; kt += 32) {
    __syncthreads();
#pragma unroll
    for (int c = 0; c < 2; c++) {
      int ch = c * 256 + tid;
      *(short8*)&As[ch >> 2][(ch & 3) * 8] = sA[c];
      if (split) *(short8*)&Asl[ch >> 2][(ch & 3) * 8] = sAl[c];
    }
    *(short8*)&Bs[tid >> 2][(tid & 3) * 8] = sB;
    if (split) *(short8*)&Bsl[tid >> 2][(tid & 3) * 8] = sBl;
    __syncthreads();
    if (kt + 32 < 512) ldtile(kt + 32);
    short8 af[4], bf_[2], afl[4], bfl[2];
#pragma unroll
    for (int mi = 0; mi < 4; mi++) af[mi] = *(const short8*)&As[wm * 64 + mi * 16 + r16][g * 8];
#pragma unroll
    for (int ni = 0; ni < 2; ni++) bf_[ni] = *(const short8*)&Bs[wn * 32 + ni * 16 + r16][g * 8];
    if (split) {
#pragma unroll
      for (int mi = 0; mi < 4; mi++) afl[mi] = *(const short8*)&Asl[wm * 64 + mi * 16 + r16][g * 8];
#pragma unroll
      for (int ni = 0; ni < 2; ni++) bfl[ni] = *(const short8*)&Bsl[wn * 32 + ni * 16 + r16][g * 8];
    }
#pragma unroll
    for (int mi = 0; mi < 4; mi++)
#pragma unroll
      for (int ni = 0; ni < 2; ni++) {
        acc[mi][ni] = mfma16(af[mi], bf_[ni], acc[mi][ni]);
        if (split) {
          acc[mi][ni] = mfma16(af[mi], bfl[ni], acc[mi][ni]);
          acc[mi][ni] = mfma16(afl[mi], bf_[ni], acc[mi][ni]);
        }
      }
  }
#pragma unroll
  for (int mi = 0; mi < 4; mi++)
#pragma unroll
    for (int ni = 0; ni < 2; ni++) {
      int col = bn + wn * 32 + ni * 16 + r16;
      int row0 = bm + wm * 64 + mi * 16 + g * 4;
      if (split) {
#pragma unroll
        for (int j = 0; j < 4; j++) {
          size_t oi = (size_t)(row0 + j) * 1024 + col;
          float v = acc[mi][ni][j];
          u16 hh = f2bf(v);
          qkh[oi] = hh;
          qkl[oi] = f2bf(v - bf2f(hh));
        }
      } else {
        // V transposed: vT[vcol][row]; 4 row-consecutive values -> one 8B store
        int vcol = col - 1024;
        ushort4 pk;
        pk.x = f2bf(acc[mi][ni][0]);
        pk.y = f2bf(acc[mi][ni][1]);
        pk.z = f2bf(acc[mi][ni][2]);
        pk.w = f2bf(acc[mi][ni][3]);
        *(ushort4*)(vT + (size_t)vcol * 4096 + row0) = pk;
      }
    }
}

// ---------------- generic GEMM ----------------
template <int MF, int NF, int EPI>
__global__ __launch_bounds__(256) void gemm_g(const u16* __restrict__ A, const u16* __restrict__ BT,
                                              const float* __restrict__ res, const float* __restrict__ bias,
                                              u16* __restrict__ outb, float* __restrict__ outf,
                                              int N, int K) {
  constexpr int BM = 32 * MF, BN = 32 * NF;
  constexpr int CA = (BM * 4 + 255) / 256, CB = (BN * 4 + 255) / 256;
  __shared__ __align__(16) u16 As[BM][40], Bs[BN][40];
  const int tid = threadIdx.x, lane = tid & 63, wv = tid >> 6;
  const int wm = wv >> 1, wn = wv & 1, g = lane >> 4, r16 = lane & 15;
  const int bm = blockIdx.x * BM, bn = blockIdx.y * BN;
  short8 sA[CA], sB[CB];
  auto ldtile = [&](int kt) {
#pragma unroll
    for (int c = 0; c < CA; c++) {
      int ch = c * 256 + tid;
      if (ch < BM * 4) sA[c] = ld8(A + (size_t)(bm + (ch >> 2)) * K + kt + (ch & 3) * 8);
    }
#pragma unroll
    for (int c = 0; c < CB; c++) {
      int ch = c * 256 + tid;
      if (ch < BN * 4) sB[c] = ld8(BT + (size_t)(bn + (ch >> 2)) * K + kt + (ch & 3) * 8);
    }
  };
  f32x4 acc[MF][NF] = {};
  ldtile(0);
  for (int kt = 0; kt < K; kt += 32) {
    __syncthreads();
#pragma unroll
    for (int c = 0; c < CA; c++) {
      int ch = c * 256 + tid;
      if (ch < BM * 4) *(short8*)&As[ch >> 2][(ch & 3) * 8] = sA[c];
    }
#pragma unroll
    for (int c = 0; c < CB; c++) {
      int ch = c * 256 + tid;
      if (ch < BN * 4) *(short8*)&Bs[ch >> 2][(ch & 3) * 8] = sB[c];
    }
    __syncthreads();
    if (kt + 32 < K) ldtile(kt + 32);
    short8 af[MF], bf_[NF];
#pragma unroll
    for (int mi = 0; mi < MF; mi++) af[mi] = *(const short8*)&As[wm * 16 * MF + mi * 16 + r16][g * 8];
#pragma unroll
    for (int ni = 0; ni < NF; ni++) bf_[ni] = *(const short8*)&Bs[wn * 16 * NF + ni * 16 + r16][g * 8];
#pragma unroll
    for (int mi = 0; mi < MF; mi++)
#pragma unroll
      for (int ni = 0; ni < NF; ni++) acc[mi][ni] = mfma16(af[mi], bf_[ni], acc[mi][ni]);
  }
#pragma unroll
  for (int mi = 0; mi < MF; mi++)
#pragma unroll
    for (int ni = 0; ni < NF; ni++) {
      int col = bn + wn * 16 * NF + ni * 16 + r16;
      int row0 = bm + wm * 16 * MF + mi * 16 + g * 4;
#pragma unroll
      for (int j = 0; j < 4; j++) {
        size_t oi = (size_t)(row0 + j) * N + col;
        float v = acc[mi][ni][j];
        if (EPI == 1) {
          outf[oi] = v + res[oi];
        } else if (EPI == 2) {
          outb[oi] = f2bf(v + bias[col]);
        } else {
          float u = v + bias[col];
          float gl = 0.5f * u * (1.0f + erff(u * 0.70710678118f));
          outf[oi] = gl + res[oi];
        }
      }
    }
}

// ---------------- flash attention v9: swapped QK^T + in-register softmax ----------------
// QBLK=64 (4 waves x 16 rows), KVBLK=128, grid (32,16). Q/K from qk[4096][1024] hi/lo;
// V from pre-transposed vT[512][4096].
// Swapped QK^T: s[f] = mfma(K_frag, Q_frag) -> lane (g,r16) holds S[qrow=r16][kv=f*16+g*4+reg].
// Softmax per lane (one q-row), 2+2 shfl_xor reduces; P stored as packed b64 (reg-consecutive kv).
// PV unchanged (pa b128 read = A-frag of P).
__global__ __launch_bounds__(256) void attn_kernel(const u16* __restrict__ qkh,
                                                   const u16* __restrict__ qkl,
                                                   const u16* __restrict__ vT,
                                                   u16* __restrict__ o) {
  constexpr int SK = 72, SV = 136, SP = 136;
  __shared__ __align__(16) u16 Kh[128 * SK], Kl[128 * SK], Vt[64 * SV];
  __shared__ __align__(16) u16 Pl[4][16 * SP];
  const int tid = threadIdx.x, lane = tid & 63, w = tid >> 6;
  const int g = lane >> 4, r16 = lane & 15;
  const int qb = blockIdx.x * 64;
  const int b = blockIdx.y >> 3, h = blockIdx.y & 7;
  const size_t bbase = (size_t)b * 2048 * 1024;
  const u16* Qh = qkh + bbase + h * 64;
  const u16* Ql = qkl + bbase + h * 64;
  const u16* KgH = qkh + bbase + 512 + h * 64;
  const u16* KgL = qkl + bbase + 512 + h * 64;
  const u16* Vtg = vT + (size_t)h * 64 * 4096 + (size_t)b * 2048;  // row d (0..63), col kv

  const int qrow = qb + w * 16 + r16;
  short8 qh[2], qlo[2];
#pragma unroll
  for (int ks = 0; ks < 2; ks++) {
    qh[ks] = ld8(Qh + (size_t)qrow * 1024 + ks * 32 + g * 8);
    qlo[ks] = ld8(Ql + (size_t)qrow * 1024 + ks * 32 + g * 8);
  }

  f32x4 oacc[4] = {};
  float m_r = -3e38f, l_r = 0.f;  // stats for q-row r16 (lane-owned)

  const int vd0 = tid >> 4, vkv = (tid & 15) * 8;
  short8 kA[4], kB[4], vS[4];
  auto ldkv = [&](int kt) {
#pragma unroll
    for (int c = 0; c < 4; c++) {
      int ch = c * 256 + tid;
      int kr = ch >> 3, kc = (ch & 7) * 8;
      kA[c] = ld8(KgH + (size_t)(kt + kr) * 1024 + kc);
      kB[c] = ld8(KgL + (size_t)(kt + kr) * 1024 + kc);
    }
#pragma unroll
    for (int c = 0; c < 4; c++)
      vS[c] = ld8(Vtg + (size_t)(vd0 + c * 16) * 4096 + kt + vkv);
  };
  ldkv(0);

  for (int kt = 0; kt < 2048; kt += 128) {
    __syncthreads();
#pragma unroll
    for (int c = 0; c < 4; c++) {
      int ch = c * 256 + tid;
      int kr = ch >> 3, kc = (ch & 7) * 8;
      *(short8*)&Kh[kr * SK + kc] = kA[c];
      *(short8*)&Kl[kr * SK + kc] = kB[c];
    }
#pragma unroll
    for (int c = 0; c < 4; c++)
      *(short8*)&Vt[(vd0 + c * 16) * SV + vkv] = vS[c];
    __syncthreads();
    if (kt + 128 < 2048) ldkv(kt + 128);
    // ---- QK^T SWAPPED (split: hi*hi + hi*lo + lo*hi): s[f] = K x Q ----
    f32x4 s[8];
#pragma unroll
    for (int f = 0; f < 8; f++) {
      s[f] = f32x4{0.f, 0.f, 0.f, 0.f};
#pragma unroll
      for (int ks = 0; ks < 2; ks++) {
        short8 bh = *(const short8*)&Kh[(f * 16 + r16) * SK + ks * 32 + g * 8];
        short8 bl = *(const short8*)&Kl[(f * 16 + r16) * SK + ks * 32 + g * 8];
        s[f] = mfma16(bh, qh[ks], s[f]);
        s[f] = mfma16(bl, qh[ks], s[f]);
        s[f] = mfma16(bh, qlo[ks], s[f]);
      }
    }
    // ---- in-register online softmax (lane owns q-row r16) ----
    constexpr float SCL2 = 0.125f * 1.44269504f;
    float a[8][4];
    float vm = -3e38f;
#pragma unroll
    for (int f = 0; f < 8; f++)
#pragma unroll
      for (int r = 0; r < 4; r++) {
        a[f][r] = s[f][r] * SCL2;
        vm = fmaxf(vm, a[f][r]);
      }
    vm = fmaxf(vm, __shfl_xor(vm, 16));
    vm = fmaxf(vm, __shfl_xor(vm, 32));
    float mn = fmaxf(m_r, vm);
    float scl = exp2fast(m_r - mn);
    m_r = mn;
    float rs = 0.f;
#pragma unroll
    for (int f = 0; f < 8; f++) {
      float e0 = exp2fast(a[f][0] - mn), e1 = exp2fast(a[f][1] - mn);
      float e2 = exp2fast(a[f][2] - mn), e3 = exp2fast(a[f][3] - mn);
      rs += (e0 + e1) + (e2 + e3);
      u32 u0, u1, u2, u3;
      __builtin_memcpy(&u0, &e0, 4);
      __builtin_memcpy(&u1, &e1, 4);
      __builtin_memcpy(&u2, &e2, 4);
      __builtin_memcpy(&u3, &e3, 4);
      uint2 pk;
      pk.x = (u0 >> 16) | (u1 & 0xFFFF0000u);  // bf16 pair (kv+0, kv+1), truncation
      pk.y = (u2 >> 16) | (u3 & 0xFFFF0000u);  // (kv+2, kv+3)
      *(uint2*)&Pl[w][r16 * SP + f * 16 + g * 4] = pk;  // 8B store, kv-consecutive
    }
    rs += __shfl_xor(rs, 16);
    rs += __shfl_xor(rs, 32);
    l_r = l_r * scl + rs;
    // rescale oacc rows g*4+j with that row's scl (held at lanes with r16 == g*4+j)
#pragma unroll
    for (int j = 0; j < 4; j++) {
      float sj = __shfl(scl, (g << 4) + (g << 2) + j);
#pragma unroll
      for (int dt = 0; dt < 4; dt++) oacc[dt][j] *= sj;
    }
    // ---- P@V ----
#pragma unroll
    for (int ks = 0; ks < 4; ks++) {
      short8 pa = *(const short8*)&Pl[w][r16 * SP + ks * 32 + g * 8];
#pragma unroll
      for (int dt = 0; dt < 4; dt++) {
        short8 vb = *(const short8*)&Vt[(dt * 16 + r16) * SV + ks * 32 + g * 8];
        oacc[dt] = mfma16(pa, vb, oacc[dt]);
      }
    }
  }
  // epilogue: normalize rows g*4+j by 1/l of that row
#pragma unroll
  for (int j = 0; j < 4; j++) {
    float lj = __shfl(l_r, (g << 4) + (g << 2) + j);
    float il = 1.f / lj;
    int row = b * 2048 + qb + w * 16 + g * 4 + j;
#pragma unroll
    for (int dt = 0; dt < 4; dt++) {
      int col = h * 64 + dt * 16 + r16;
      o[(size_t)row * 512 + col] = f2bf(oacc[dt][j] * il);
    }
  }
}

// ---------------- launcher ----------------
extern "C" void kernel_launch(void* const* d_in, const int* in_sizes, int n_in,
                              void* d_out, int out_size, void* d_ws, size_t ws_size,
                              hipStream_t stream) {
  const float* z = (const float*)d_in[0];
  const float* head_w = (const float*)d_in[1];
  const float* w_o = (const float*)d_in[2];
  const float* ln_w = (const float*)d_in[3];
  const float* ln_b = (const float*)d_in[4];
  const float* w1 = (const float*)d_in[5];
  const float* b1 = (const float*)d_in[6];
  const float* w2 = (const float*)d_in[7];
  const float* b2 = (const float*)d_in[8];
  float* out = (float*)d_out;

  size_t off = 0;
  auto alc = [&](size_t n) {
    void* p = (char*)d_ws + off;
    off += (n + 255) & ~(size_t)255;
    return p;
  };
  u16* x_hi = (u16*)alc((size_t)4096 * 512 * 2);
  u16* x_lo = (u16*)alc((size_t)4096 * 512 * 2);
  u16* wqh = (u16*)alc((size_t)1536 * 512 * 2);
  u16* wql = (u16*)alc((size_t)1536 * 512 * 2);
  u16* woT = (u16*)alc((size_t)512 * 512 * 2);
  u16* w1T = (u16*)alc((size_t)128 * 512 * 2);
  u16* w2T = (u16*)alc((size_t)512 * 128 * 2);
  u16* qkh = (u16*)alc((size_t)4096 * 1024 * 2);
  u16* qkl = (u16*)alc((size_t)4096 * 1024 * 2);
  u16* vT = (u16*)alc((size_t)512 * 4096 * 2);
  u16* ob = (u16*)alc((size_t)4096 * 512 * 2);
  float* z2 = (float*)alc((size_t)4096 * 512 * 4);
  u16* tb = (u16*)alc((size_t)4096 * 128 * 2);

  prep_all<<<4608, 256, 0, stream>>>(head_w, w_o, w1, w2, wqh, wql, woT, w1T, w2T);

  // LN1: z -> x hi/lo
  ln_kernel<<<1024, 256, 0, stream>>>(z, ln_w, ln_b, x_hi, x_lo);

  // QKV projection (r4 tiling); V written transposed to vT
  gemm_qkv<<<dim3(32, 24), 256, 0, stream>>>(x_hi, x_lo, wqh, wql, qkh, qkl, vT);

  // flash attention (swapped QK^T, in-register softmax)
  attn_kernel<<<dim3(32, 16), 256, 0, stream>>>(qkh, qkl, vT, ob);

  // z2 = o @ w_o + z
  gemm_g<2, 2, 1><<<dim3(64, 8), 256, 0, stream>>>(ob, woT, z, nullptr, nullptr, z2, 512, 512);

  // LN2
  ln_kernel<<<1024, 256, 0, stream>>>(z2, ln_w, ln_b, x_hi, x_lo);

  // t = y @ w1 + b1
  gemm_g<1, 2, 2><<<dim3(128, 2), 256, 0, stream>>>(x_hi, w1T, nullptr, b1, tb, nullptr, 128, 512);

  // out = gelu(t @ w2 + b2) + z2
  gemm_g<2, 2, 3><<<dim3(64, 8), 256, 0, stream>>>(tb, w2T, z2, b2, nullptr, out, 512, 128);
}